// Round 10
// baseline (2748.348 us; speedup 1.0000x reference)
//
#include <hip/hip_runtime.h>
#include <hip/hip_bf16.h>
#include <hip/hip_fp8.h>

#define N_TOK 4096
#define H_DIM 1024
#define V_DIM 50257
#define IGNORE_IDX (-100)

// fp8 fast-path params
#define BM 128
#define BN 128
#define BK 128                               /* fp8: 128 bytes per row per step */
#define NSTEP (H_DIM / BK)                   /* 8 */
#define NCHUNK ((V_DIM + BN - 1) / BN)       /* 393 */

// fallback params
#define LDT 72

typedef __attribute__((ext_vector_type(8))) short bf16x8;
typedef __attribute__((ext_vector_type(4))) float f32x4;
typedef __attribute__((ext_vector_type(4))) int i32x4;
typedef __attribute__((ext_vector_type(8))) int i32x8;

union Pack8 { __hip_bfloat162 h2[4]; int4 v; };

#define SCALE1 0x7F7F7F7Fu  /* e8m0 = 127 per byte -> 2^0 = 1.0 for every 32-block */

__device__ __forceinline__ void gload16(const void* g, void* l) {
    __builtin_amdgcn_global_load_lds(
        (const __attribute__((address_space(1))) unsigned int*)g,
        (__attribute__((address_space(3))) unsigned int*)l,
        16, 0, 0);
}

__device__ __forceinline__ int pack4_fp8(float a, float b, float c, float d) {
#if __has_builtin(__builtin_amdgcn_cvt_pk_fp8_f32)
    int w = __builtin_amdgcn_cvt_pk_fp8_f32(a, b, 0, false);
    w = __builtin_amdgcn_cvt_pk_fp8_f32(c, d, w, true);
    return w;
#else
    __hip_fp8_e4m3 q0(a), q1(b), q2(c), q3(d);
    return (int)q0.__x | ((int)q1.__x << 8) | ((int)q2.__x << 16) | ((int)q3.__x << 24);
#endif
}

// ---------------- cvt kernels: fp32 -> fp8 e4m3, natural order ----------------
__global__ __launch_bounds__(256) void cvt_x8_kernel(const float* __restrict__ x,
                                                     unsigned char* __restrict__ xb8) {
    size_t e = (size_t)blockIdx.x * 256 + threadIdx.x;   // granule of 16 floats
    const float4* s = reinterpret_cast<const float4*>(x) + e * 4;
    float4 f0 = s[0], f1 = s[1], f2 = s[2], f3 = s[3];
    int4 o;
    o.x = pack4_fp8(f0.x, f0.y, f0.z, f0.w);
    o.y = pack4_fp8(f1.x, f1.y, f1.z, f1.w);
    o.z = pack4_fp8(f2.x, f2.y, f2.z, f2.w);
    o.w = pack4_fp8(f3.x, f3.y, f3.z, f3.w);
    reinterpret_cast<int4*>(xb8)[e] = o;
}

__global__ __launch_bounds__(256) void cvt_w8_kernel(const float* __restrict__ W,
                                                     unsigned char* __restrict__ Wb8) {
    const size_t total = (size_t)V_DIM * H_DIM / 16;     // granules of 16
    size_t stride = (size_t)gridDim.x * 256;
    for (size_t e = (size_t)blockIdx.x * 256 + threadIdx.x; e < total; e += stride) {
        const float4* s = reinterpret_cast<const float4*>(W) + e * 4;
        float4 f0 = s[0], f1 = s[1], f2 = s[2], f3 = s[3];
        int4 o;
        o.x = pack4_fp8(f0.x, f0.y, f0.z, f0.w);
        o.y = pack4_fp8(f1.x, f1.y, f1.z, f1.w);
        o.z = pack4_fp8(f2.x, f2.y, f2.z, f2.w);
        o.w = pack4_fp8(f3.x, f3.y, f3.z, f3.w);
        reinterpret_cast<int4*>(Wb8)[e] = o;
    }
}

// ---------------- MX-FP8 GEMM (spill-free rework of R9) ----------------
// grid = (N/BM, NCHUNK), block = 256 (4 waves, 2x2 of 64x64)
// Layout verified by R9 pass: A/B frag (16x16x128): row=lane&15, k=(lane>>4)*32+i.
// LDS slot (r,g) holds natural granule (r, g^(r&7)); lane reads slots (2lg)^(r&7), ^1.
// Scales pinned to 1.0 -> numerics identical to non-scaled fp8.
__global__ __launch_bounds__(256, 3) void ce_gemm_mx8(
        const unsigned char* __restrict__ xb8,   // [N][H] fp8
        const unsigned char* __restrict__ Wb8,   // [V][H] fp8
        const int* __restrict__ tgt,
        float2* __restrict__ partials,           // [N][NCHUNK]
        float* __restrict__ picked) {            // [N]
    __shared__ __align__(16) char lA[BM * BK];   // 16 KB
    __shared__ __align__(16) char lB[BN * BK];   // 16 KB
    __shared__ float2 mergebuf[BM][2];
    __shared__ int ltgt[BM];

    const int tid  = threadIdx.x;
    const int mb   = blockIdx.x;
    const int vb   = blockIdx.y;
    const int rbase = mb * BM;
    const int cbase = vb * BN;
    const int lane = tid & 63;
    const int wid  = tid >> 6;
    const int wr   = wid >> 1;
    const int wc   = wid & 1;
    const int l15  = lane & 15;
    const int lg   = lane >> 4;

    if (tid < BM) ltgt[tid] = tgt[rbase + tid];

    // staging: granule G = it*256 + tid; r = it*32 + (tid>>3); g = tid&7; src granule g^(r&7).
    // r&7 == (tid>>3)&7 for all it -> swizzle column identical across it -> A uses base+stride.
    const int r0 = tid >> 3;
    const int gsw = (tid & 7) ^ (r0 & 7);
    const unsigned char* pa = xb8 + (size_t)(rbase + r0) * H_DIM + gsw * 16;
    const unsigned char* pb0;
    const unsigned char* pb1;
    const unsigned char* pb2;
    const unsigned char* pb3;
    {
        int v0 = cbase + r0;       if (v0 >= V_DIM) v0 = V_DIM - 1;
        int v1 = cbase + 32 + r0;  if (v1 >= V_DIM) v1 = V_DIM - 1;
        int v2 = cbase + 64 + r0;  if (v2 >= V_DIM) v2 = V_DIM - 1;
        int v3 = cbase + 96 + r0;  if (v3 >= V_DIM) v3 = V_DIM - 1;
        pb0 = Wb8 + (size_t)v0 * H_DIM + gsw * 16;
        pb1 = Wb8 + (size_t)v1 * H_DIM + gsw * 16;
        pb2 = Wb8 + (size_t)v2 * H_DIM + gsw * 16;
        pb3 = Wb8 + (size_t)v3 * H_DIM + gsw * 16;
    }

    // read byte-offsets: slot of lane's lo granule (2lg); partner = ^16
    int aoffb[4], boffb[4];
    #pragma unroll
    for (int m = 0; m < 4; ++m) {
        int r = wr * 64 + m * 16 + l15;
        aoffb[m] = r * 128 + (((lg * 2) ^ (r & 7)) << 4);
    }
    #pragma unroll
    for (int n = 0; n < 4; ++n) {
        int r = wc * 64 + n * 16 + l15;
        boffb[n] = r * 128 + (((lg * 2) ^ (r & 7)) << 4);
    }

#define LDS32(base, off) __builtin_shufflevector(                              \
        *reinterpret_cast<const i32x4*>((base) + (off)),                       \
        *reinterpret_cast<const i32x4*>((base) + ((off) ^ 16)),                \
        0, 1, 2, 3, 4, 5, 6, 7)

    f32x4 acc[4][4] = {};

    for (int s = 0; s < NSTEP; ++s) {
        __syncthreads();                         // prior MFMA reads done before overwrite
        gload16(pa,                 lA + (0 * 256 + wid * 64) * 16);
        gload16(pa + 32 * H_DIM,    lA + (1 * 256 + wid * 64) * 16);
        gload16(pa + 64 * H_DIM,    lA + (2 * 256 + wid * 64) * 16);
        gload16(pa + 96 * H_DIM,    lA + (3 * 256 + wid * 64) * 16);
        gload16(pb0, lB + (0 * 256 + wid * 64) * 16);
        gload16(pb1, lB + (1 * 256 + wid * 64) * 16);
        gload16(pb2, lB + (2 * 256 + wid * 64) * 16);
        gload16(pb3, lB + (3 * 256 + wid * 64) * 16);
        pa += BK; pb0 += BK; pb1 += BK; pb2 += BK; pb3 += BK;
        __syncthreads();                         // compiler drains vmcnt before barrier

        i32x8 vb0 = LDS32(lB, boffb[0]);
        i32x8 vb1 = LDS32(lB, boffb[1]);
        i32x8 vb2 = LDS32(lB, boffb[2]);
        i32x8 vb3 = LDS32(lB, boffb[3]);
        #pragma unroll
        for (int m = 0; m < 4; ++m) {
            i32x8 va = LDS32(lA, aoffb[m]);
            acc[m][0] = __builtin_amdgcn_mfma_scale_f32_16x16x128_f8f6f4(
                va, vb0, acc[m][0], 0, 0, 0, SCALE1, 0, SCALE1);
            acc[m][1] = __builtin_amdgcn_mfma_scale_f32_16x16x128_f8f6f4(
                va, vb1, acc[m][1], 0, 0, 0, SCALE1, 0, SCALE1);
            acc[m][2] = __builtin_amdgcn_mfma_scale_f32_16x16x128_f8f6f4(
                va, vb2, acc[m][2], 0, 0, 0, SCALE1, 0, SCALE1);
            acc[m][3] = __builtin_amdgcn_mfma_scale_f32_16x16x128_f8f6f4(
                va, vb3, acc[m][3], 0, 0, 0, SCALE1, 0, SCALE1);
        }
    }
#undef LDS32

    // ---- fused epilogue: per-row (max, sumexp) over this 128-col chunk + target pick ----
    // C layout (shape-determined): col = lane&15, row = (lane>>4)*4 + reg
    #pragma unroll
    for (int m = 0; m < 4; ++m) {
        #pragma unroll
        for (int j = 0; j < 4; ++j) {
            int rl = wr * 64 + m * 16 + lg * 4 + j;
            int tg = ltgt[rl];
            float v4[4];
            float vmax = -INFINITY;
            #pragma unroll
            for (int n = 0; n < 4; ++n) {
                int cg = cbase + wc * 64 + n * 16 + l15;
                float val = acc[m][n][j];
                bool ok = cg < V_DIM;
                v4[n] = ok ? val : -INFINITY;
                if (ok && tg == cg) picked[rbase + rl] = val;
                vmax = fmaxf(vmax, v4[n]);
            }
            #pragma unroll
            for (int msk = 1; msk <= 8; msk <<= 1)
                vmax = fmaxf(vmax, __shfl_xor(vmax, msk));
            float ssum = 0.f;
            #pragma unroll
            for (int n = 0; n < 4; ++n)
                ssum += (v4[n] == -INFINITY) ? 0.f : __expf(v4[n] - vmax);
            #pragma unroll
            for (int msk = 1; msk <= 8; msk <<= 1)
                ssum += __shfl_xor(ssum, msk);
            if (l15 == 0) mergebuf[rl][wc] = make_float2(vmax, ssum);
        }
    }
    __syncthreads();
    if (tid < BM) {
        float2 p0 = mergebuf[tid][0], p1 = mergebuf[tid][1];
        float M = fmaxf(p0.x, p1.x);
        float sm = 0.f;
        if (p0.x > -INFINITY) sm += p0.y * __expf(p0.x - M);
        if (p1.x > -INFINITY) sm += p1.y * __expf(p1.x - M);
        partials[(size_t)(rbase + tid) * NCHUNK + vb] = make_float2(M, sm);
    }
}

// ---------------- FALLBACK: bf16 cvt_x + fp32-W GEMM (round-1 path) ----------------
__global__ __launch_bounds__(256) void cvt_x_kernel(const float* __restrict__ x,
                                                    __hip_bfloat16* __restrict__ xb) {
    size_t e = (size_t)blockIdx.x * 256 + threadIdx.x;
    const float4* s = reinterpret_cast<const float4*>(x) + e * 2;
    float4 a = s[0], b = s[1];
    Pack8 p;
    p.h2[0] = __float22bfloat162_rn(make_float2(a.x, a.y));
    p.h2[1] = __float22bfloat162_rn(make_float2(a.z, a.w));
    p.h2[2] = __float22bfloat162_rn(make_float2(b.x, b.y));
    p.h2[3] = __float22bfloat162_rn(make_float2(b.z, b.w));
    reinterpret_cast<int4*>(xb)[e] = p.v;
}

__global__ __launch_bounds__(256) void ce_gemm_kernel(
        const __hip_bfloat16* __restrict__ xb, const float* __restrict__ W,
        const int* __restrict__ tgt, float2* __restrict__ partials, float* __restrict__ picked) {
    __shared__ __hip_bfloat16 lA[BM * LDT];
    __shared__ __hip_bfloat16 lB[BN * LDT];
    __shared__ float2 mergebuf[BM][2];
    __shared__ int ltgt[BM];
    const int tid = threadIdx.x, mb = blockIdx.x, vb = blockIdx.y;
    const int rbase = mb * BM, cbase = vb * BN;
    const int lane = tid & 63, wid = tid >> 6;
    const int wr = wid >> 1, wc = wid & 1, l15 = lane & 15, lg = lane >> 4;
    if (tid < BM) ltgt[tid] = tgt[rbase + tid];
    f32x4 acc[4][4] = {};
    for (int s = 0; s < H_DIM / 64; ++s) {
        const int k0 = s * 64;
        __syncthreads();
        #pragma unroll
        for (int it = 0; it < 4; ++it) {
            int e = it * 256 + tid, r = e >> 3, c8 = e & 7;
            int4 v = *reinterpret_cast<const int4*>(xb + (size_t)(rbase + r) * H_DIM + k0 + c8 * 8);
            *reinterpret_cast<int4*>(&lA[r * LDT + c8 * 8]) = v;
        }
        #pragma unroll
        for (int it = 0; it < 4; ++it) {
            int e = it * 256 + tid, r = e >> 3, c8 = e & 7;
            int v = cbase + r; if (v >= V_DIM) v = V_DIM - 1;
            const float4* src = reinterpret_cast<const float4*>(W + (size_t)v * H_DIM + k0 + c8 * 8);
            float4 f0 = src[0], f1 = src[1];
            Pack8 p;
            p.h2[0] = __float22bfloat162_rn(make_float2(f0.x, f0.y));
            p.h2[1] = __float22bfloat162_rn(make_float2(f0.z, f0.w));
            p.h2[2] = __float22bfloat162_rn(make_float2(f1.x, f1.y));
            p.h2[3] = __float22bfloat162_rn(make_float2(f1.z, f1.w));
            *reinterpret_cast<int4*>(&lB[r * LDT + c8 * 8]) = p.v;
        }
        __syncthreads();
        #pragma unroll
        for (int kk = 0; kk < 2; ++kk) {
            bf16x8 af[4], bfr[4];
            #pragma unroll
            for (int m = 0; m < 4; ++m)
                af[m] = *reinterpret_cast<const bf16x8*>(&lA[(wr * 64 + m * 16 + l15) * LDT + kk * 32 + lg * 8]);
            #pragma unroll
            for (int n = 0; n < 4; ++n)
                bfr[n] = *reinterpret_cast<const bf16x8*>(&lB[(wc * 64 + n * 16 + l15) * LDT + kk * 32 + lg * 8]);
            #pragma unroll
            for (int m = 0; m < 4; ++m)
                #pragma unroll
                for (int n = 0; n < 4; ++n)
                    acc[m][n] = __builtin_amdgcn_mfma_f32_16x16x32_bf16(af[m], bfr[n], acc[m][n], 0, 0, 0);
        }
    }
    #pragma unroll
    for (int m = 0; m < 4; ++m) {
        #pragma unroll
        for (int j = 0; j < 4; ++j) {
            int rl = wr * 64 + m * 16 + lg * 4 + j;
            int tg = ltgt[rl];
            float v4[4]; float vmax = -INFINITY;
            #pragma unroll
            for (int n = 0; n < 4; ++n) {
                int cg = cbase + wc * 64 + n * 16 + l15;
                float val = acc[m][n][j];
                bool ok = cg < V_DIM;
                v4[n] = ok ? val : -INFINITY;
                if (ok && tg == cg) picked[rbase + rl] = val;
                vmax = fmaxf(vmax, v4[n]);
            }
            #pragma unroll
            for (int msk = 1; msk <= 8; msk <<= 1) vmax = fmaxf(vmax, __shfl_xor(vmax, msk));
            float ssum = 0.f;
            #pragma unroll
            for (int n = 0; n < 4; ++n) ssum += (v4[n] == -INFINITY) ? 0.f : __expf(v4[n] - vmax);
            #pragma unroll
            for (int msk = 1; msk <= 8; msk <<= 1) ssum += __shfl_xor(ssum, msk);
            if (l15 == 0) mergebuf[rl][wc] = make_float2(vmax, ssum);
        }
    }
    __syncthreads();
    if (tid < BM) {
        float2 p0 = mergebuf[tid][0], p1 = mergebuf[tid][1];
        float M = fmaxf(p0.x, p1.x);
        float sm = 0.f;
        if (p0.x > -INFINITY) sm += p0.y * __expf(p0.x - M);
        if (p1.x > -INFINITY) sm += p1.y * __expf(p1.x - M);
        partials[(size_t)(rbase + tid) * NCHUNK + vb] = make_float2(M, sm);
    }
}

// ---------------- combine + final ----------------
__global__ __launch_bounds__(256) void ce_combine_kernel(
        const float2* __restrict__ partials, const float* __restrict__ picked,
        const int* __restrict__ tgt, float2* __restrict__ blockSums, int nchunk) {
    __shared__ float2 wsum[4];
    int tid = threadIdx.x, lane = tid & 63, wave = tid >> 6;
    int w = blockIdx.x * 4 + wave;
    float sum = 0.f, cnt = 0.f;
    for (int row = w; row < N_TOK; row += 256) {
        float m = -INFINITY, sacc = 0.f;
        for (int c = lane; c < nchunk; c += 64) {
            float2 p = partials[(size_t)row * nchunk + c];
            float M = fmaxf(m, p.x);
            sacc = sacc * __expf(m - M) + p.y * __expf(p.x - M);
            m = M;
        }
        #pragma unroll
        for (int msk = 1; msk < 64; msk <<= 1) {
            float om = __shfl_xor(m, msk), os = __shfl_xor(sacc, msk);
            float M = fmaxf(m, om);
            sacc = sacc * __expf(m - M) + os * __expf(om - M);
            m = M;
        }
        if (lane == 0) {
            int t = tgt[row];
            if (t != IGNORE_IDX) { sum += (m + __logf(sacc)) - picked[row]; cnt += 1.f; }
        }
    }
    if (lane == 0) wsum[wave] = make_float2(sum, cnt);
    __syncthreads();
    if (tid == 0) {
        float S = 0.f, C = 0.f;
        #pragma unroll
        for (int i = 0; i < 4; ++i) { S += wsum[i].x; C += wsum[i].y; }
        blockSums[blockIdx.x] = make_float2(S, C);
    }
}

__global__ void ce_final_kernel(const float2* __restrict__ blockSums, float* __restrict__ out) {
    int lane = threadIdx.x;
    float2 p = blockSums[lane];
    float S = p.x, C = p.y;
    #pragma unroll
    for (int msk = 1; msk < 64; msk <<= 1) { S += __shfl_xor(S, msk); C += __shfl_xor(C, msk); }
    if (lane == 0) out[0] = S / fmaxf(C, 1.f);
}

extern "C" void kernel_launch(void* const* d_in, const int* in_sizes, int n_in,
                              void* d_out, int out_size, void* d_ws, size_t ws_size,
                              hipStream_t stream) {
    const float* x   = (const float*)d_in[0];
    const int*   tgt = (const int*)d_in[1];
    const float* W   = (const float*)d_in[2];
    float* out = (float*)d_out;
    char* ws = (char*)d_ws;

    if (ws_size >= ((size_t)80 << 20)) {
        // fast path: xb8@0 (4.2MB), Wb8@8MB (51.5MB), partials@60MB (12.9MB),
        // picked@76MB (16KB), blockSums@77MB
        unsigned char* xb8 = (unsigned char*)ws;
        unsigned char* Wb8 = (unsigned char*)(ws + ((size_t)8 << 20));
        float2* partials   = (float2*)(ws + ((size_t)60 << 20));
        float*  picked     = (float*)(ws + ((size_t)76 << 20));
        float2* blockSums  = (float2*)(ws + ((size_t)77 << 20));

        cvt_x8_kernel<<<(N_TOK * H_DIM) / (256 * 16), 256, 0, stream>>>(x, xb8);
        cvt_w8_kernel<<<2048, 256, 0, stream>>>(W, Wb8);
        dim3 grid(N_TOK / BM, NCHUNK);
        ce_gemm_mx8<<<grid, 256, 0, stream>>>(xb8, Wb8, tgt, partials, picked);
        ce_combine_kernel<<<64, 256, 0, stream>>>(partials, picked, tgt, blockSums, NCHUNK);
        ce_final_kernel<<<1, 64, 0, stream>>>(blockSums, out);
    } else {
        // fallback (round-1 layout): bf16 x, fp32 W staged with in-register cvt
        __hip_bfloat16* xb = (__hip_bfloat16*)ws;
        float2* partials   = (float2*)(ws + (8u << 20));
        float*  picked     = (float*)(ws + (21u << 20));
        float2* blockSums  = (float2*)(ws + (21u << 20) + (64u << 10));

        cvt_x_kernel<<<(N_TOK * H_DIM) / (256 * 8), 256, 0, stream>>>(x, xb);
        dim3 grid(N_TOK / BM, NCHUNK);
        ce_gemm_kernel<<<grid, 256, 0, stream>>>(xb, W, tgt, partials, picked);
        ce_combine_kernel<<<64, 256, 0, stream>>>(partials, picked, tgt, blockSums, NCHUNK);
        ce_final_kernel<<<1, 64, 0, stream>>>(blockSums, out);
    }
}

// Round 11
// 399.301 us; speedup vs baseline: 6.8829x; 6.8829x over previous
//
#include <hip/hip_runtime.h>
#include <hip/hip_bf16.h>
#include <hip/hip_fp8.h>

#define N_TOK 4096
#define H_DIM 1024
#define V_DIM 50257
#define IGNORE_IDX (-100)

// fp8 fast-path params
#define BM 128
#define BN 128
#define BK 128                               /* fp8: 128 bytes per row per step */
#define NSTEP (H_DIM / BK)                   /* 8 */
#define NCHUNK ((V_DIM + BN - 1) / BN)       /* 393 */

// fallback params
#define LDT 72

typedef __attribute__((ext_vector_type(8))) short bf16x8;
typedef __attribute__((ext_vector_type(4))) float f32x4;
typedef long longx2 __attribute__((ext_vector_type(2)));

union Pack8 { __hip_bfloat162 h2[4]; int4 v; };

__device__ __forceinline__ void gload16(const void* g, void* l) {
    __builtin_amdgcn_global_load_lds(
        (const __attribute__((address_space(1))) unsigned int*)g,
        (__attribute__((address_space(3))) unsigned int*)l,
        16, 0, 0);
}

__device__ __forceinline__ int pack4_fp8(float a, float b, float c, float d) {
#if __has_builtin(__builtin_amdgcn_cvt_pk_fp8_f32)
    int w = __builtin_amdgcn_cvt_pk_fp8_f32(a, b, 0, false);
    w = __builtin_amdgcn_cvt_pk_fp8_f32(c, d, w, true);
    return w;
#else
    __hip_fp8_e4m3 q0(a), q1(b), q2(c), q3(d);
    return (int)q0.__x | ((int)q1.__x << 8) | ((int)q2.__x << 16) | ((int)q3.__x << 24);
#endif
}

// ---------------- cvt kernels: fp32 -> fp8 e4m3, PERMUTED layout ----------------
// Within each 128B K-block of a row: element e = kk*32+lg*8+i  (kk 0..3, lg 0..3, i 0..7)
// stored at byte  o*16 + (kk&1)*8 + i  with  o = (kk>>1)*4 + lg.
// => lane (l15,lg)'s operands for kk-pair j live in ONE 16B granule o = j*4+lg.
// One thread produces one output granule (16B) from two 8-float source runs (+0, +32).
__global__ __launch_bounds__(256) void cvt_x8p_kernel(const float* __restrict__ x,
                                                      unsigned char* __restrict__ xb8) {
    size_t E = (size_t)blockIdx.x * 256 + threadIdx.x;   // output granule index
    int o = (int)(E & 7);
    size_t blk = E >> 3;                                  // 128-elem block (row-major)
    const float* s = x + (blk << 7) + ((size_t)(o >> 2) << 6) + ((o & 3) << 3);
    float4 f0 = *(const float4*)(s);
    float4 f1 = *(const float4*)(s + 4);
    float4 f2 = *(const float4*)(s + 32);
    float4 f3 = *(const float4*)(s + 36);
    int4 out;
    out.x = pack4_fp8(f0.x, f0.y, f0.z, f0.w);
    out.y = pack4_fp8(f1.x, f1.y, f1.z, f1.w);
    out.z = pack4_fp8(f2.x, f2.y, f2.z, f2.w);
    out.w = pack4_fp8(f3.x, f3.y, f3.z, f3.w);
    reinterpret_cast<int4*>(xb8)[E] = out;
}

__global__ __launch_bounds__(256) void cvt_w8p_kernel(const float* __restrict__ W,
                                                      unsigned char* __restrict__ Wb8) {
    const size_t total = (size_t)V_DIM * H_DIM / 16;      // output granules
    size_t stride = (size_t)gridDim.x * 256;
    for (size_t E = (size_t)blockIdx.x * 256 + threadIdx.x; E < total; E += stride) {
        int o = (int)(E & 7);
        size_t blk = E >> 3;
        const float* s = W + (blk << 7) + ((size_t)(o >> 2) << 6) + ((o & 3) << 3);
        float4 f0 = *(const float4*)(s);
        float4 f1 = *(const float4*)(s + 4);
        float4 f2 = *(const float4*)(s + 32);
        float4 f3 = *(const float4*)(s + 36);
        int4 out;
        out.x = pack4_fp8(f0.x, f0.y, f0.z, f0.w);
        out.y = pack4_fp8(f1.x, f1.y, f1.z, f1.w);
        out.z = pack4_fp8(f2.x, f2.y, f2.z, f2.w);
        out.w = pack4_fp8(f3.x, f3.y, f3.z, f3.w);
        reinterpret_cast<int4*>(Wb8)[E] = out;
    }
}

// ---------------- FP8 GEMM: R2 structure, BK=128, b128 reads, zero-conflict swizzle ----------------
// grid = (N/BM, NCHUNK), block = 256 (4 waves, 2x2 of 64x64)
// LDS slot (r, g) holds permuted-array granule (r, g^(r&7)); dest linear (rule #21).
// Read: lane (l15,lg), kk-pair j: b128 at r*128 + (((j*4+lg)^(r&7))<<4)  == R2's proven pattern.
__global__ __launch_bounds__(256, 4) void ce_gemm_fp8(
        const unsigned char* __restrict__ xb8,   // [N][H] fp8 permuted
        const unsigned char* __restrict__ Wb8,   // [V][H] fp8 permuted
        const int* __restrict__ tgt,
        float2* __restrict__ partials,           // [N][NCHUNK]
        float* __restrict__ picked) {            // [N]
    __shared__ __align__(16) char lA[BM * BK];   // 16 KB
    __shared__ __align__(16) char lB[BN * BK];   // 16 KB
    __shared__ float2 mergebuf[BM][2];
    __shared__ int ltgt[BM];

    const int tid  = threadIdx.x;
    const int mb   = blockIdx.x;     // row tile fast -> consecutive blocks share W chunk (L2/L3)
    const int vb   = blockIdx.y;
    const int rbase = mb * BM;
    const int cbase = vb * BN;
    const int lane = tid & 63;
    const int wid  = tid >> 6;
    const int wr   = wid >> 1;
    const int wc   = wid & 1;
    const int l15  = lane & 15;
    const int lg   = lane >> 4;

    if (tid < BM) ltgt[tid] = tgt[rbase + tid];

    // staging: granule G = it*256 + tid (16B); r = G>>3, g = G&7;
    // source granule = g^(r&7) of the PERMUTED array; dest = linear G*16.
    const unsigned char* srcA[4];
    const unsigned char* srcB[4];
    #pragma unroll
    for (int it = 0; it < 4; ++it) {
        int G = it * 256 + tid;
        int r = G >> 3, g = G & 7;
        int gs = g ^ (r & 7);
        srcA[it] = xb8 + (size_t)(rbase + r) * H_DIM + gs * 16;
        int vr = cbase + r; if (vr >= V_DIM) vr = V_DIM - 1;   // clamp; masked in epilogue
        srcB[it] = Wb8 + (size_t)vr * H_DIM + gs * 16;
    }

    // read byte-offsets (j=0 granule; j=1 is ^64 since slot bit2 toggles)
    int aoffb[4], boffb[4];
    #pragma unroll
    for (int m = 0; m < 4; ++m) {
        int r = wr * 64 + m * 16 + l15;
        aoffb[m] = r * 128 + ((lg ^ (r & 7)) << 4);
    }
    #pragma unroll
    for (int n = 0; n < 4; ++n) {
        int r = wc * 64 + n * 16 + l15;
        boffb[n] = r * 128 + ((lg ^ (r & 7)) << 4);
    }

    f32x4 acc[4][4] = {};

    for (int s = 0; s < NSTEP; ++s) {
        const int k0 = s * BK;
        __syncthreads();                         // prior MFMA reads done before overwrite
        #pragma unroll
        for (int it = 0; it < 4; ++it) {
            gload16(srcA[it] + k0, lA + (it * 256 + wid * 64) * 16);
            gload16(srcB[it] + k0, lB + (it * 256 + wid * 64) * 16);
        }
        __syncthreads();                         // compiler drains vmcnt before barrier

        longx2 va[4][2], vb[4][2];
        #pragma unroll
        for (int m = 0; m < 4; ++m) {
            va[m][0] = *reinterpret_cast<const longx2*>(lA + aoffb[m]);
            va[m][1] = *reinterpret_cast<const longx2*>(lA + (aoffb[m] ^ 64));
        }
        #pragma unroll
        for (int n = 0; n < 4; ++n) {
            vb[n][0] = *reinterpret_cast<const longx2*>(lB + boffb[n]);
            vb[n][1] = *reinterpret_cast<const longx2*>(lB + (boffb[n] ^ 64));
        }
        #pragma unroll
        for (int kk = 0; kk < 4; ++kk)
            #pragma unroll
            for (int m = 0; m < 4; ++m)
                #pragma unroll
                for (int n = 0; n < 4; ++n)
                    acc[m][n] = __builtin_amdgcn_mfma_f32_16x16x32_fp8_fp8(
                        va[m][kk >> 1][kk & 1], vb[n][kk >> 1][kk & 1], acc[m][n], 0, 0, 0);
    }

    // ---- fused epilogue: per-row (max, sumexp) over this 128-col chunk + target pick ----
    // C layout (dtype-independent): col = lane&15, row = (lane>>4)*4 + reg
    #pragma unroll
    for (int m = 0; m < 4; ++m) {
        #pragma unroll
        for (int j = 0; j < 4; ++j) {
            int rl = wr * 64 + m * 16 + lg * 4 + j;
            int tg = ltgt[rl];
            float v4[4];
            float vmax = -INFINITY;
            #pragma unroll
            for (int n = 0; n < 4; ++n) {
                int cg = cbase + wc * 64 + n * 16 + l15;
                float val = acc[m][n][j];
                bool ok = cg < V_DIM;
                v4[n] = ok ? val : -INFINITY;
                if (ok && tg == cg) picked[rbase + rl] = val;
                vmax = fmaxf(vmax, v4[n]);
            }
            #pragma unroll
            for (int msk = 1; msk <= 8; msk <<= 1)
                vmax = fmaxf(vmax, __shfl_xor(vmax, msk));
            float ssum = 0.f;
            #pragma unroll
            for (int n = 0; n < 4; ++n)
                ssum += (v4[n] == -INFINITY) ? 0.f : __expf(v4[n] - vmax);
            #pragma unroll
            for (int msk = 1; msk <= 8; msk <<= 1)
                ssum += __shfl_xor(ssum, msk);
            if (l15 == 0) mergebuf[rl][wc] = make_float2(vmax, ssum);
        }
    }
    __syncthreads();
    if (tid < BM) {
        float2 p0 = mergebuf[tid][0], p1 = mergebuf[tid][1];
        float M = fmaxf(p0.x, p1.x);
        float sm = 0.f;
        if (p0.x > -INFINITY) sm += p0.y * __expf(p0.x - M);
        if (p1.x > -INFINITY) sm += p1.y * __expf(p1.x - M);
        partials[(size_t)(rbase + tid) * NCHUNK + vb] = make_float2(M, sm);
    }
}

// ---------------- FALLBACK: bf16 cvt_x + fp32-W GEMM (round-1 path) ----------------
__global__ __launch_bounds__(256) void cvt_x_kernel(const float* __restrict__ x,
                                                    __hip_bfloat16* __restrict__ xb) {
    size_t e = (size_t)blockIdx.x * 256 + threadIdx.x;
    const float4* s = reinterpret_cast<const float4*>(x) + e * 2;
    float4 a = s[0], b = s[1];
    Pack8 p;
    p.h2[0] = __float22bfloat162_rn(make_float2(a.x, a.y));
    p.h2[1] = __float22bfloat162_rn(make_float2(a.z, a.w));
    p.h2[2] = __float22bfloat162_rn(make_float2(b.x, b.y));
    p.h2[3] = __float22bfloat162_rn(make_float2(b.z, b.w));
    reinterpret_cast<int4*>(xb)[e] = p.v;
}

__global__ __launch_bounds__(256) void ce_gemm_kernel(
        const __hip_bfloat16* __restrict__ xb, const float* __restrict__ W,
        const int* __restrict__ tgt, float2* __restrict__ partials, float* __restrict__ picked) {
    __shared__ __hip_bfloat16 lA[BM * LDT];
    __shared__ __hip_bfloat16 lB[BN * LDT];
    __shared__ float2 mergebuf[BM][2];
    __shared__ int ltgt[BM];
    const int tid = threadIdx.x, mb = blockIdx.x, vb = blockIdx.y;
    const int rbase = mb * BM, cbase = vb * BN;
    const int lane = tid & 63, wid = tid >> 6;
    const int wr = wid >> 1, wc = wid & 1, l15 = lane & 15, lg = lane >> 4;
    if (tid < BM) ltgt[tid] = tgt[rbase + tid];
    f32x4 acc[4][4] = {};
    for (int s = 0; s < H_DIM / 64; ++s) {
        const int k0 = s * 64;
        __syncthreads();
        #pragma unroll
        for (int it = 0; it < 4; ++it) {
            int e = it * 256 + tid, r = e >> 3, c8 = e & 7;
            int4 v = *reinterpret_cast<const int4*>(xb + (size_t)(rbase + r) * H_DIM + k0 + c8 * 8);
            *reinterpret_cast<int4*>(&lA[r * LDT + c8 * 8]) = v;
        }
        #pragma unroll
        for (int it = 0; it < 4; ++it) {
            int e = it * 256 + tid, r = e >> 3, c8 = e & 7;
            int v = cbase + r; if (v >= V_DIM) v = V_DIM - 1;
            const float4* src = reinterpret_cast<const float4*>(W + (size_t)v * H_DIM + k0 + c8 * 8);
            float4 f0 = src[0], f1 = src[1];
            Pack8 p;
            p.h2[0] = __float22bfloat162_rn(make_float2(f0.x, f0.y));
            p.h2[1] = __float22bfloat162_rn(make_float2(f0.z, f0.w));
            p.h2[2] = __float22bfloat162_rn(make_float2(f1.x, f1.y));
            p.h2[3] = __float22bfloat162_rn(make_float2(f1.z, f1.w));
            *reinterpret_cast<int4*>(&lB[r * LDT + c8 * 8]) = p.v;
        }
        __syncthreads();
        #pragma unroll
        for (int kk = 0; kk < 2; ++kk) {
            bf16x8 af[4], bfr[4];
            #pragma unroll
            for (int m = 0; m < 4; ++m)
                af[m] = *reinterpret_cast<const bf16x8*>(&lA[(wr * 64 + m * 16 + l15) * LDT + kk * 32 + lg * 8]);
            #pragma unroll
            for (int n = 0; n < 4; ++n)
                bfr[n] = *reinterpret_cast<const bf16x8*>(&lB[(wc * 64 + n * 16 + l15) * LDT + kk * 32 + lg * 8]);
            #pragma unroll
            for (int m = 0; m < 4; ++m)
                #pragma unroll
                for (int n = 0; n < 4; ++n)
                    acc[m][n] = __builtin_amdgcn_mfma_f32_16x16x32_bf16(af[m], bfr[n], acc[m][n], 0, 0, 0);
        }
    }
    #pragma unroll
    for (int m = 0; m < 4; ++m) {
        #pragma unroll
        for (int j = 0; j < 4; ++j) {
            int rl = wr * 64 + m * 16 + lg * 4 + j;
            int tg = ltgt[rl];
            float v4[4]; float vmax = -INFINITY;
            #pragma unroll
            for (int n = 0; n < 4; ++n) {
                int cg = cbase + wc * 64 + n * 16 + l15;
                float val = acc[m][n][j];
                bool ok = cg < V_DIM;
                v4[n] = ok ? val : -INFINITY;
                if (ok && tg == cg) picked[rbase + rl] = val;
                vmax = fmaxf(vmax, v4[n]);
            }
            #pragma unroll
            for (int msk = 1; msk <= 8; msk <<= 1) vmax = fmaxf(vmax, __shfl_xor(vmax, msk));
            float ssum = 0.f;
            #pragma unroll
            for (int n = 0; n < 4; ++n) ssum += (v4[n] == -INFINITY) ? 0.f : __expf(v4[n] - vmax);
            #pragma unroll
            for (int msk = 1; msk <= 8; msk <<= 1) ssum += __shfl_xor(ssum, msk);
            if (l15 == 0) mergebuf[rl][wc] = make_float2(vmax, ssum);
        }
    }
    __syncthreads();
    if (tid < BM) {
        float2 p0 = mergebuf[tid][0], p1 = mergebuf[tid][1];
        float M = fmaxf(p0.x, p1.x);
        float sm = 0.f;
        if (p0.x > -INFINITY) sm += p0.y * __expf(p0.x - M);
        if (p1.x > -INFINITY) sm += p1.y * __expf(p1.x - M);
        partials[(size_t)(rbase + tid) * NCHUNK + vb] = make_float2(M, sm);
    }
}

// ---------------- combine + final ----------------
__global__ __launch_bounds__(256) void ce_combine_kernel(
        const float2* __restrict__ partials, const float* __restrict__ picked,
        const int* __restrict__ tgt, float2* __restrict__ blockSums, int nchunk) {
    __shared__ float2 wsum[4];
    int tid = threadIdx.x, lane = tid & 63, wave = tid >> 6;
    int w = blockIdx.x * 4 + wave;
    float sum = 0.f, cnt = 0.f;
    for (int row = w; row < N_TOK; row += 256) {
        float m = -INFINITY, sacc = 0.f;
        for (int c = lane; c < nchunk; c += 64) {
            float2 p = partials[(size_t)row * nchunk + c];
            float M = fmaxf(m, p.x);
            sacc = sacc * __expf(m - M) + p.y * __expf(p.x - M);
            m = M;
        }
        #pragma unroll
        for (int msk = 1; msk < 64; msk <<= 1) {
            float om = __shfl_xor(m, msk), os = __shfl_xor(sacc, msk);
            float M = fmaxf(m, om);
            sacc = sacc * __expf(m - M) + os * __expf(om - M);
            m = M;
        }
        if (lane == 0) {
            int t = tgt[row];
            if (t != IGNORE_IDX) { sum += (m + __logf(sacc)) - picked[row]; cnt += 1.f; }
        }
    }
    if (lane == 0) wsum[wave] = make_float2(sum, cnt);
    __syncthreads();
    if (tid == 0) {
        float S = 0.f, C = 0.f;
        #pragma unroll
        for (int i = 0; i < 4; ++i) { S += wsum[i].x; C += wsum[i].y; }
        blockSums[blockIdx.x] = make_float2(S, C);
    }
}

__global__ void ce_final_kernel(const float2* __restrict__ blockSums, float* __restrict__ out) {
    int lane = threadIdx.x;
    float2 p = blockSums[lane];
    float S = p.x, C = p.y;
    #pragma unroll
    for (int msk = 1; msk < 64; msk <<= 1) { S += __shfl_xor(S, msk); C += __shfl_xor(C, msk); }
    if (lane == 0) out[0] = S / fmaxf(C, 1.f);
}

extern "C" void kernel_launch(void* const* d_in, const int* in_sizes, int n_in,
                              void* d_out, int out_size, void* d_ws, size_t ws_size,
                              hipStream_t stream) {
    const float* x   = (const float*)d_in[0];
    const int*   tgt = (const int*)d_in[1];
    const float* W   = (const float*)d_in[2];
    float* out = (float*)d_out;
    char* ws = (char*)d_ws;

    if (ws_size >= ((size_t)80 << 20)) {
        // fast path: xb8@0 (4.2MB), Wb8@8MB (51.5MB), partials@60MB (12.9MB),
        // picked@76MB (16KB), blockSums@77MB
        unsigned char* xb8 = (unsigned char*)ws;
        unsigned char* Wb8 = (unsigned char*)(ws + ((size_t)8 << 20));
        float2* partials   = (float2*)(ws + ((size_t)60 << 20));
        float*  picked     = (float*)(ws + ((size_t)76 << 20));
        float2* blockSums  = (float2*)(ws + ((size_t)77 << 20));

        cvt_x8p_kernel<<<(N_TOK * H_DIM) / (256 * 16), 256, 0, stream>>>(x, xb8);
        cvt_w8p_kernel<<<2048, 256, 0, stream>>>(W, Wb8);
        dim3 grid(N_TOK / BM, NCHUNK);
        ce_gemm_fp8<<<grid, 256, 0, stream>>>(xb8, Wb8, tgt, partials, picked);
        ce_combine_kernel<<<64, 256, 0, stream>>>(partials, picked, tgt, blockSums, NCHUNK);
        ce_final_kernel<<<1, 64, 0, stream>>>(blockSums, out);
    } else {
        // fallback (round-1 layout): bf16 x, fp32 W staged with in-register cvt
        __hip_bfloat16* xb = (__hip_bfloat16*)ws;
        float2* partials   = (float2*)(ws + (8u << 20));
        float*  picked     = (float*)(ws + (21u << 20));
        float2* blockSums  = (float2*)(ws + (21u << 20) + (64u << 10));

        cvt_x_kernel<<<(N_TOK * H_DIM) / (256 * 8), 256, 0, stream>>>(x, xb);
        dim3 grid(N_TOK / BM, NCHUNK);
        ce_gemm_kernel<<<grid, 256, 0, stream>>>(xb, W, tgt, partials, picked);
        ce_combine_kernel<<<64, 256, 0, stream>>>(partials, picked, tgt, blockSums, NCHUNK);
        ce_final_kernel<<<1, 64, 0, stream>>>(blockSums, out);
    }
}